// Round 1
// baseline (667.586 us; speedup 1.0000x reference)
//
#include <hip/hip_runtime.h>

// MMSE-PIC detector: B=32768, M=16, S=8, NBPS=4 (QAM16 Gray), NUM_ITER=2, EPS=1e-4
// One 64-lane wave per batch element; all per-batch state in LDS.

#define EPS_F 1e-4f
#define NITER 2
#define INV_SQRT10 0.31622776601683794f

__device__ __forceinline__ float pt_re(int p) {
    return (1.0f - 2.0f * (float)((p >> 3) & 1)) * (1.0f + 2.0f * (float)((p >> 1) & 1)) * INV_SQRT10;
}
__device__ __forceinline__ float pt_im(int p) {
    return (1.0f - 2.0f * (float)((p >> 2) & 1)) * (1.0f + 2.0f * (float)(p & 1)) * INV_SQRT10;
}
__device__ __forceinline__ float log_sigmoid(float x) {
    return fminf(x, 0.0f) - log1pf(expf(-fabsf(x)));
}

__global__ __launch_bounds__(64)
void mmse_pic_kernel(const float* __restrict__ y_re, const float* __restrict__ y_im,
                     const float* __restrict__ h_re, const float* __restrict__ h_im,
                     const float* __restrict__ prior,
                     const float* __restrict__ s_re, const float* __restrict__ s_im,
                     float* __restrict__ out)
{
    const int b    = blockIdx.x;
    const int lane = threadIdx.x;
    const size_t bs = (size_t)b;

    __shared__ float Ar[16][17], Ai[16][17];   // S (complex), becomes L in-place
    __shared__ float Hr[16][9],  Hi[16][9];    // h cols 0..7, y col 8 (whitened in place)
    __shared__ float Gre[8][8],  Gim[8][8];    // g = h^H h
    __shared__ float GR[16][17];               // real-valued gram [[Re,-Im],[Im,Re]]
    __shared__ float AUG[16][33];              // [a | a_inv] Gauss-Jordan workspace
    __shared__ float colk[16];
    __shared__ float Ypr[8][8],  Ypi[8][8];    // y_mf_pic [i][j]
    __shared__ float ymfr[8], ymfi[8];
    __shared__ float logit[8][17];             // per-point log priors; reused as exps
    __shared__ float llrA[8][4], llrD[8][4];
    __shared__ float xhr[8], xhi[8], varx[8];
    __shared__ float muA[16], zA[16];
    __shared__ float noeff[8];

    // ---- load ----
    {
        const float* pr = s_re + bs * 256;
        const float* pi = s_im + bs * 256;
        for (int t = lane; t < 256; t += 64) { Ar[t >> 4][t & 15] = pr[t]; Ai[t >> 4][t & 15] = pi[t]; }
        const float* phr = h_re + bs * 128;
        const float* phi = h_im + bs * 128;
        for (int t = lane; t < 128; t += 64) { Hr[t >> 3][t & 7] = phr[t]; Hi[t >> 3][t & 7] = phi[t]; }
        if (lane < 16) { Hr[lane][8] = y_re[bs * 16 + lane]; Hi[lane][8] = y_im[bs * 16 + lane]; }
        if (lane < 32) { llrD[lane >> 2][lane & 3] = prior[bs * 32 + lane]; }
    }

    // ---- complex Cholesky (right-looking, maintain full Hermitian trailing block) ----
    for (int k = 0; k < 16; ++k) {
        __syncthreads();
        float d  = sqrtf(Ar[k][k]);
        float id = 1.0f / d;
        if (lane == k)                      { Ar[k][k] = d; Ai[k][k] = 0.0f; }
        else if (lane > k && lane < 16)     { Ar[lane][k] *= id; Ai[lane][k] *= id; }
        __syncthreads();
        for (int t = lane; t < 256; t += 64) {
            int i = t >> 4, j = t & 15;
            if (i > k && j > k) {
                float lr = Ar[i][k], li = Ai[i][k];
                float mr = Ar[j][k], mi = Ai[j][k];
                Ar[i][j] -= lr * mr + li * mi;   // A[i][j] -= L[i][k]*conj(L[j][k])
                Ai[i][j] -= li * mr - lr * mi;
            }
        }
    }

    // ---- forward substitution: [h | y] <- L^-1 [h | y]  (9 columns) ----
    for (int k = 0; k < 16; ++k) {
        __syncthreads();
        float id = 1.0f / Ar[k][k];
        if (lane < 9) { Hr[k][lane] *= id; Hi[k][lane] *= id; }
        __syncthreads();
        for (int t = lane; t < 144; t += 64) {
            int i = t / 9, c = t - 9 * i;
            if (i > k) {
                float lr = Ar[i][k], li = Ai[i][k];
                float hr = Hr[k][c], hi = Hi[k][c];
                Hr[i][c] -= lr * hr - li * hi;
                Hi[i][c] -= lr * hi + li * hr;
            }
        }
    }
    __syncthreads();

    // ---- Gram g = h^H h (one entry per lane) and y_mf = h^H y (lanes 0..7) ----
    {
        int i = lane >> 3, j = lane & 7;
        float sr = 0.f, si = 0.f;
        #pragma unroll
        for (int m = 0; m < 16; ++m) {
            float ar = Hr[m][i], aii = Hi[m][i];
            float br = Hr[m][j], bi  = Hi[m][j];
            sr += ar * br + aii * bi;
            si += ar * bi - aii * br;
        }
        Gre[i][j] = sr; Gim[i][j] = si;
    }
    if (lane < 8) {
        float yr = 0.f, yi = 0.f;
        #pragma unroll
        for (int m = 0; m < 16; ++m) {
            float ar = Hr[m][lane], aii = Hi[m][lane];
            float br = Hr[m][8],    bi  = Hi[m][8];
            yr += ar * br + aii * bi;
            yi += ar * bi - aii * br;
        }
        ymfr[lane] = yr; ymfi[lane] = yi;
    }
    __syncthreads();
    // gr = [[Re g, -Im g],[Im g, Re g]]
    for (int t = lane; t < 256; t += 64) {
        int i = t >> 4, j = t & 15;
        float v;
        if (i < 8) v = (j < 8) ? Gre[i][j]     : -Gim[i][j - 8];
        else       v = (j < 8) ? Gim[i - 8][j] :  Gre[i - 8][j - 8];
        GR[i][j] = v;
    }

    // ---- PIC iterations ----
    for (int it = 0; it < NITER; ++it) {
        __syncthreads();
        if (lane < 32) llrA[lane >> 2][lane & 3] = llrD[lane >> 2][lane & 3];
        __syncthreads();

        // symbol logits from llr_a: logit[s][p] = sum_k log_sigmoid(asgn[p][k]*llr_a[s][k])
        for (int t = lane; t < 128; t += 64) {
            int s = t >> 4, p = t & 15;
            float acc = 0.f;
            #pragma unroll
            for (int kb = 0; kb < 4; ++kb) {
                float sg = ((p >> (3 - kb)) & 1) ? 1.0f : -1.0f;
                acc += log_sigmoid(sg * llrA[s][kb]);
            }
            logit[s][p] = acc;
        }
        __syncthreads();

        // moments: softmax over 16 points (lanes 0..7)
        if (lane < 8) {
            float mx = -1e30f;
            #pragma unroll
            for (int p = 0; p < 16; ++p) mx = fmaxf(mx, logit[lane][p]);
            float se = 0.f, mr = 0.f, mi = 0.f, e2 = 0.f;
            #pragma unroll
            for (int p = 0; p < 16; ++p) {
                float w = expf(logit[lane][p] - mx);
                float re = pt_re(p), im = pt_im(p);
                se += w; mr += w * re; mi += w * im; e2 += w * (re * re + im * im);
            }
            float inv = 1.0f / se;
            mr *= inv; mi *= inv; e2 *= inv;
            xhr[lane] = mr; xhi[lane] = mi;
            varx[lane] = e2 - (mr * mr + mi * mi);
        }
        __syncthreads();

        // y_mf_pic[i][j] = y_mf[i] + g[i][j]*x[j] - (g x)[i]   (one entry per lane)
        {
            int i = lane >> 3, j = lane & 7;
            float sr = 0.f, si = 0.f;
            #pragma unroll
            for (int jj = 0; jj < 8; ++jj) {
                float gr3 = Gre[i][jj], gi3 = Gim[i][jj];
                float xr2 = xhr[jj],    xi2 = xhi[jj];
                sr += gr3 * xr2 - gi3 * xi2;
                si += gr3 * xi2 + gi3 * xr2;
            }
            float gr2 = Gre[i][j], gi2 = Gim[i][j];
            float xr = xhr[j], xi = xhi[j];
            Ypr[i][j] = ymfr[i] + (gr2 * xr - gi2 * xi) - sr;
            Ypi[i][j] = ymfi[i] + (gr2 * xi + gi2 * xr) - si;
        }
        // build augmented [a | I],  a = gr * var2_col + I
        for (int t = lane; t < 256; t += 64) {
            int i = t >> 4, j = t & 15;
            float v2 = varx[j & 7];
            AUG[i][j]      = GR[i][j] * v2 + ((i == j) ? 1.0f : 0.0f);
            AUG[i][j + 16] = (i == j) ? 1.0f : 0.0f;
        }

        // Gauss-Jordan inverse (no pivoting: a = I + PSD-similar, pivots >= ~1)
        for (int k = 0; k < 16; ++k) {
            __syncthreads();
            if (lane < 16) colk[lane] = AUG[lane][k];
            __syncthreads();
            float ip = 1.0f / colk[k];
            if (lane < 32) AUG[k][lane] *= ip;
            __syncthreads();
            for (int t = lane; t < 512; t += 64) {
                int i = t >> 5, j = t & 31;
                if (i != k) AUG[i][j] -= colk[i] * AUG[k][j];
            }
        }
        __syncthreads();

        // mu = diag(a_inv @ gr); z = rowwise a_inv . v_r / mu  (lanes 0..15)
        if (lane < 16) {
            float m = 0.f;
            #pragma unroll
            for (int j = 0; j < 16; ++j) m += AUG[lane][16 + j] * GR[j][lane];
            muA[lane] = m;
            int r = lane & 7;
            float zz = 0.f;
            #pragma unroll
            for (int j = 0; j < 16; ++j) {
                float v = (j < 8) ? Ypr[j][r] : Ypi[j - 8][r];
                zz += AUG[lane][16 + j] * v;
            }
            zA[lane] = zz / m;
        }
        __syncthreads();

        // new x_hat and effective noise (lanes 0..7)
        if (lane < 8) {
            xhr[lane] = zA[lane];
            xhi[lane] = zA[lane + 8];
            float m = muA[lane];
            noeff[lane] = fmaxf(1.0f - varx[lane] * m, EPS_F) / m;
        }
        __syncthreads();

        // demap: exps[s][p] = -|x-pt|^2/no_eff + logit[s][p]  (overwrite logit)
        for (int t = lane; t < 128; t += 64) {
            int s = t >> 4, p = t & 15;
            float dr = xhr[s] - pt_re(p), di = xhi[s] - pt_im(p);
            logit[s][p] = -(dr * dr + di * di) / noeff[s] + logit[s][p];
        }
        __syncthreads();

        // max-log LLR per (s, bit)  (lanes 0..31)
        if (lane < 32) {
            int s = lane >> 2, kb = lane & 3;
            float m1 = -1e30f, m0 = -1e30f;
            #pragma unroll
            for (int p = 0; p < 16; ++p) {
                float e = logit[s][p];
                if ((p >> (3 - kb)) & 1) m1 = fmaxf(m1, e);
                else                      m0 = fmaxf(m0, e);
            }
            llrD[s][kb] = m1 - m0;
        }
    }
    __syncthreads();

    // extrinsic output
    if (lane < 32) {
        out[bs * 32 + lane] = llrD[lane >> 2][lane & 3] - llrA[lane >> 2][lane & 3];
    }
}

extern "C" void kernel_launch(void* const* d_in, const int* in_sizes, int n_in,
                              void* d_out, int out_size, void* d_ws, size_t ws_size,
                              hipStream_t stream) {
    const float* y_re  = (const float*)d_in[0];
    const float* y_im  = (const float*)d_in[1];
    const float* h_re  = (const float*)d_in[2];
    const float* h_im  = (const float*)d_in[3];
    const float* prior = (const float*)d_in[4];
    const float* s_re  = (const float*)d_in[5];
    const float* s_im  = (const float*)d_in[6];
    float* out = (float*)d_out;

    const int B = in_sizes[0] / 16;   // y_re is [B, M=16]
    mmse_pic_kernel<<<dim3(B), dim3(64), 0, stream>>>(
        y_re, y_im, h_re, h_im, prior, s_re, s_im, out);
}

// Round 2
// 373.611 us; speedup vs baseline: 1.7868x; 1.7868x over previous
//
#include <hip/hip_runtime.h>

// MMSE-PIC detector: B=32768, M=16, S=8, QAM16 Gray, 2 iterations.
// One 64-lane wave per batch. Round 2: algebraic restructuring.
//   - X = S^-1 [h|y] via single Gauss-Jordan (16 steps) instead of Cholesky+fsub (32 steps)
//   - complex 8x8 inner solve [A | b | g] instead of real 16x16 inverse
//   - z_c[i] = (w[i] + C[i][i] x[i]) / Re(C[i][i]),  w = A^-1 b, C = A^-1 g,  b = y_mf - g x
//   - shuffle-parallel moments / LLR, log-sigmoid table (64 distinct values, 1/lane)

#define EPS_F 1e-4f
#define INV_SQRT10 0.31622776601683794f

__device__ __forceinline__ float pt_re(int p) {
    return (1.0f - 2.0f * (float)((p >> 3) & 1)) * (1.0f + 2.0f * (float)((p >> 1) & 1)) * INV_SQRT10;
}
__device__ __forceinline__ float pt_im(int p) {
    return (1.0f - 2.0f * (float)((p >> 2) & 1)) * (1.0f + 2.0f * (float)(p & 1)) * INV_SQRT10;
}

__global__ __launch_bounds__(64)
void mmse_pic_kernel(const float* __restrict__ y_re, const float* __restrict__ y_im,
                     const float* __restrict__ h_re, const float* __restrict__ h_im,
                     const float* __restrict__ prior,
                     const float* __restrict__ s_re, const float* __restrict__ s_im,
                     float* __restrict__ out)
{
    const int b = blockIdx.x, lane = threadIdx.x;
    const size_t bs = (size_t)b;

    __shared__ float Sr[16][27], Si[16][27];   // augmented [S(0-15) | h(16-23) | y(24)] -> X = S^-1[h|y]
    __shared__ float Hor[16][9], Hoi[16][9];   // original h
    __shared__ float Gr_[8][9],  Gi_[8][9];    // g = h^H S^-1 h
    __shared__ float A2r[8][18], A2i[8][18];   // [A(0-7) | b(8) | g->C(9-16)]
    __shared__ float logit_[8][17];
    __shared__ float lsig[8][4][2];            // log_sigmoid table
    __shared__ float llrA_[8][4], llrD_[8][4];
    __shared__ float xr_[8], xi_[8], vx_[8], ymr_[8], ymi_[8], ne_[8];

    // ---- load (vectorized) ----
    {
        const float4* pr4 = (const float4*)(s_re + bs * 256);
        const float4* pi4 = (const float4*)(s_im + bs * 256);
        float4 vr = pr4[lane], vi = pi4[lane];
        int r = lane >> 2, c = (lane & 3) << 2;
        Sr[r][c] = vr.x; Sr[r][c+1] = vr.y; Sr[r][c+2] = vr.z; Sr[r][c+3] = vr.w;
        Si[r][c] = vi.x; Si[r][c+1] = vi.y; Si[r][c+2] = vi.z; Si[r][c+3] = vi.w;
        if (lane < 32) {
            const float4* hr4 = (const float4*)(h_re + bs * 128);
            const float4* hi4 = (const float4*)(h_im + bs * 128);
            float4 hr = hr4[lane], hi = hi4[lane];
            int row = lane >> 1, col = (lane & 1) << 2;
            Hor[row][col] = hr.x; Hor[row][col+1] = hr.y; Hor[row][col+2] = hr.z; Hor[row][col+3] = hr.w;
            Hoi[row][col] = hi.x; Hoi[row][col+1] = hi.y; Hoi[row][col+2] = hi.z; Hoi[row][col+3] = hi.w;
            Sr[row][16+col] = hr.x; Sr[row][17+col] = hr.y; Sr[row][18+col] = hr.z; Sr[row][19+col] = hr.w;
            Si[row][16+col] = hi.x; Si[row][17+col] = hi.y; Si[row][18+col] = hi.z; Si[row][19+col] = hi.w;
        }
        if (lane < 16) { Sr[lane][24] = y_re[bs*16 + lane]; Si[lane][24] = y_im[bs*16 + lane]; }
        if (lane < 32) { llrD_[lane >> 2][lane & 3] = prior[bs*32 + lane]; }
    }

    // ---- Gauss-Jordan: [S | h y] -> [* | S^-1 h, S^-1 y]  (no pivoting: S is HPD) ----
    for (int k = 0; k < 16; ++k) {
        __syncthreads();
        if (lane < 25 && lane > k) {
            float pr = Sr[k][k], pi = Si[k][k];
            float dn = 1.0f / (pr*pr + pi*pi);
            float ipr = pr * dn, ipi = -pi * dn;
            float ar = Sr[k][lane], ai = Si[k][lane];
            Sr[k][lane] = ar*ipr - ai*ipi;
            Si[k][lane] = ar*ipi + ai*ipr;
        }
        __syncthreads();
        for (int jb = k + 1; jb < 25; jb += 16) {
            #pragma unroll
            for (int pas = 0; pas < 4; ++pas) {
                int t = lane + (pas << 6);
                int i = t >> 4, j = jb + (t & 15);
                if (i != k && j < 25) {
                    float mr = Sr[i][k], mi = Si[i][k];     // col k never rewritten: safe multiplier
                    float ar = Sr[k][j], ai = Si[k][j];
                    Sr[i][j] -= mr*ar - mi*ai;
                    Si[i][j] -= mr*ai + mi*ar;
                }
            }
        }
    }
    __syncthreads();

    // ---- g = h^H X_h (1 entry/lane), y_mf = h^H X_y (lanes 0..7) ----
    {
        int i = lane >> 3, j = lane & 7;
        float gr = 0.f, gi = 0.f;
        #pragma unroll
        for (int m = 0; m < 16; ++m) {
            float hr = Hor[m][i], hi = Hoi[m][i];
            float xr = Sr[m][16+j], xi = Si[m][16+j];
            gr += hr*xr + hi*xi;
            gi += hr*xi - hi*xr;
        }
        Gr_[i][j] = gr; Gi_[i][j] = gi;
    }
    if (lane < 8) {
        float yr = 0.f, yi = 0.f;
        #pragma unroll
        for (int m = 0; m < 16; ++m) {
            float hr = Hor[m][lane], hi = Hoi[m][lane];
            float cr = Sr[m][24], ci = Si[m][24];
            yr += hr*cr + hi*ci;
            yi += hr*ci - hi*cr;
        }
        ymr_[lane] = yr; ymi_[lane] = yi;
    }

    float llr_a_reg = 0.0f;
    for (int it = 0; it < 2; ++it) {
        __syncthreads();
        if (lane < 32) {
            float v = llrD_[lane >> 2][lane & 3];
            llrA_[lane >> 2][lane & 3] = v;
            llr_a_reg = v;
        }
        __syncthreads();
        // log-sigmoid table: one distinct value per lane
        {
            int s = lane >> 3, kb = (lane >> 1) & 3, sg = lane & 1;
            float v = llrA_[s][kb];
            float x = sg ? v : -v;
            lsig[s][kb][sg] = fminf(x, 0.0f) - log1pf(__expf(-fabsf(x)));
        }
        __syncthreads();
        // symbol logits: 2 per lane, 4 table adds each
        #pragma unroll
        for (int pas = 0; pas < 2; ++pas) {
            int t = lane + (pas << 6);
            int s = t >> 4, p = t & 15;
            logit_[s][p] = lsig[s][0][(p>>3)&1] + lsig[s][1][(p>>2)&1]
                         + lsig[s][2][(p>>1)&1] + lsig[s][3][p&1];
        }
        __syncthreads();
        // moments: 8 lanes per stream, 2 points per lane, butterfly reductions
        {
            int s = lane >> 3, u = lane & 7;
            float l0 = logit_[s][u], l1 = logit_[s][u+8];
            float m = fmaxf(l0, l1);
            m = fmaxf(m, __shfl_xor(m, 1));
            m = fmaxf(m, __shfl_xor(m, 2));
            m = fmaxf(m, __shfl_xor(m, 4));
            float p0r = pt_re(u),   p0i = pt_im(u);
            float p1r = pt_re(u+8), p1i = pt_im(u+8);
            float w0 = __expf(l0 - m), w1 = __expf(l1 - m);
            float se = w0 + w1;
            float mr = w0*p0r + w1*p1r;
            float mi = w0*p0i + w1*p1i;
            float e2 = w0*(p0r*p0r + p0i*p0i) + w1*(p1r*p1r + p1i*p1i);
            se += __shfl_xor(se,1); mr += __shfl_xor(mr,1); mi += __shfl_xor(mi,1); e2 += __shfl_xor(e2,1);
            se += __shfl_xor(se,2); mr += __shfl_xor(mr,2); mi += __shfl_xor(mi,2); e2 += __shfl_xor(e2,2);
            se += __shfl_xor(se,4); mr += __shfl_xor(mr,4); mi += __shfl_xor(mi,4); e2 += __shfl_xor(e2,4);
            if (u == 0) {
                float inv = 1.0f / se;
                float mxr = mr*inv, mxi = mi*inv;
                xr_[s] = mxr; xi_[s] = mxi;
                vx_[s] = e2*inv - (mxr*mxr + mxi*mxi);
            }
        }
        __syncthreads();
        // b = y_mf - g x (butterfly over j), A = I + g diag(var), copy g -> cols 9..16
        {
            int i = lane >> 3, j = lane & 7;
            float gr = Gr_[i][j], gi = Gi_[i][j];
            float xr = xr_[j], xi = xi_[j];
            float tr = gr*xr - gi*xi, ti = gr*xi + gi*xr;
            tr += __shfl_xor(tr,1); ti += __shfl_xor(ti,1);
            tr += __shfl_xor(tr,2); ti += __shfl_xor(ti,2);
            tr += __shfl_xor(tr,4); ti += __shfl_xor(ti,4);
            float v = vx_[j];
            A2r[i][j] = gr*v + (i == j ? 1.0f : 0.0f);
            A2i[i][j] = gi*v;
            A2r[i][9+j] = gr; A2i[i][9+j] = gi;
            if (j == 0) { A2r[i][8] = ymr_[i] - tr; A2i[i][8] = ymi_[i] - ti; }
        }
        // complex 8x8 GJ on [A | b | g] -> cols 8..16 = [A^-1 b | A^-1 g]
        for (int k = 0; k < 8; ++k) {
            __syncthreads();
            if (lane < 17 && lane > k) {
                float pr = A2r[k][k], pi = A2i[k][k];
                float dn = 1.0f / (pr*pr + pi*pi);
                float ipr = pr * dn, ipi = -pi * dn;
                float ar = A2r[k][lane], ai = A2i[k][lane];
                A2r[k][lane] = ar*ipr - ai*ipi;
                A2i[k][lane] = ar*ipi + ai*ipr;
            }
            __syncthreads();
            #pragma unroll
            for (int pas = 0; pas < 2; ++pas) {
                int t = lane + (pas << 6);
                int i = t >> 4, j = 1 + (t & 15);
                if (i != k && j > k) {
                    float mr = A2r[i][k], mi = A2i[i][k];
                    float ar = A2r[k][j], ai = A2i[k][j];
                    A2r[i][j] -= mr*ar - mi*ai;
                    A2i[i][j] -= mr*ai + mi*ar;
                }
            }
        }
        __syncthreads();
        // z, no_eff (lanes 0..7)
        if (lane < 8) {
            float mcr = A2r[lane][9+lane], mci = A2i[lane][9+lane]; // C[i][i]
            float mu = mcr;
            float wr = A2r[lane][8], wi = A2i[lane][8];
            float xr = xr_[lane], xi = xi_[lane];
            float im = 1.0f / mu;
            xr_[lane] = (wr + mcr*xr - mci*xi) * im;
            xi_[lane] = (wi + mcr*xi + mci*xr) * im;
            ne_[lane] = fmaxf(1.0f - vx_[lane]*mu, EPS_F) * im;
        }
        __syncthreads();
        // demap: exps = -|x - pt|^2 / no_eff + logits  (2 per lane)
        #pragma unroll
        for (int pas = 0; pas < 2; ++pas) {
            int t = lane + (pas << 6);
            int s = t >> 4, p = t & 15;
            float dr = xr_[s] - pt_re(p), di = xi_[s] - pt_im(p);
            logit_[s][p] -= (dr*dr + di*di) / ne_[s];
        }
        __syncthreads();
        // max-log LLR: lane = (s, bit, half); each lane maxes its 8 matching points
        {
            int s = lane >> 3, kb = (lane >> 1) & 3, half = lane & 1;
            int bitpos = 3 - kb;
            float m = -1e30f;
            #pragma unroll
            for (int q = 0; q < 8; ++q) {
                int low  = q & ((1 << bitpos) - 1);
                int high = (q >> bitpos) << (bitpos + 1);
                int p = high | (half << bitpos) | low;
                m = fmaxf(m, logit_[s][p]);
            }
            float other = __shfl_xor(m, 1);
            if (half == 1) llrD_[s][kb] = m - other;   // l1 - l0
        }
    }
    __syncthreads();
    if (lane < 32) {
        out[bs*32 + lane] = llrD_[lane >> 2][lane & 3] - llr_a_reg;
    }
}

extern "C" void kernel_launch(void* const* d_in, const int* in_sizes, int n_in,
                              void* d_out, int out_size, void* d_ws, size_t ws_size,
                              hipStream_t stream) {
    const float* y_re  = (const float*)d_in[0];
    const float* y_im  = (const float*)d_in[1];
    const float* h_re  = (const float*)d_in[2];
    const float* h_im  = (const float*)d_in[3];
    const float* prior = (const float*)d_in[4];
    const float* s_re  = (const float*)d_in[5];
    const float* s_im  = (const float*)d_in[6];
    float* out = (float*)d_out;

    const int B = in_sizes[0] / 16;
    mmse_pic_kernel<<<dim3(B), dim3(64), 0, stream>>>(
        y_re, y_im, h_re, h_im, prior, s_re, s_im, out);
}

// Round 3
// 285.123 us; speedup vs baseline: 2.3414x; 1.3103x over previous
//
#include <hip/hip_runtime.h>

// MMSE-PIC detector: B=32768, M=16, S=8, QAM16 Gray, 2 iterations.
// One 64-lane wave per batch, wave-synchronous (NO s_barrier: single-wave
// workgroup + in-order DS => wave_barrier() compiler fences suffice).
// Round 3: float2-packed LDS (b64 ops, conflict-free strides), unnormalized
// Gauss-Jordan (no normalize passes), register+shuffle inner 8x8 solve,
// register-resident logits.

#define EPS_F 1e-4f
#define INV_SQRT10 0.31622776601683794f
#define WSYNC() __builtin_amdgcn_wave_barrier()

__device__ __forceinline__ float rcpf(float x) { return __builtin_amdgcn_rcpf(x); }
__device__ __forceinline__ float pt_re(int p) {
    return (1.0f - 2.0f * (float)((p >> 3) & 1)) * (1.0f + 2.0f * (float)((p >> 1) & 1)) * INV_SQRT10;
}
__device__ __forceinline__ float pt_im(int p) {
    return (1.0f - 2.0f * (float)((p >> 2) & 1)) * (1.0f + 2.0f * (float)(p & 1)) * INV_SQRT10;
}

__global__ __launch_bounds__(64)
void mmse_pic_kernel(const float* __restrict__ y_re, const float* __restrict__ y_im,
                     const float* __restrict__ h_re, const float* __restrict__ h_im,
                     const float* __restrict__ prior,
                     const float* __restrict__ s_re, const float* __restrict__ s_im,
                     float* __restrict__ out)
{
    const int b = blockIdx.x, lane = threadIdx.x;
    const size_t bs = (size_t)b;

    __shared__ float2 Sc[16][28];   // [S(0-15) | h(16-23) | y(24)], complex packed
    __shared__ float2 Hc[16][10];   // original h (cols 0-7)
    __shared__ float2 xc_[8];       // x_hat
    __shared__ float2 ymc_[8];      // y_mf
    __shared__ float  vx_[8], ne_[8];
    __shared__ float  lsig[64];     // [(s<<3)|(kb<<1)|bit]
    __shared__ float  logit_[8][20];
    __shared__ float  llrD_[8][4];

    // ---- load (vectorized, interleave re/im into float2) ----
    {
        const float4* pr4 = (const float4*)(s_re + bs * 256);
        const float4* pi4 = (const float4*)(s_im + bs * 256);
        float4 vr = pr4[lane], vi = pi4[lane];
        int r = lane >> 2, c0 = (lane & 3) << 2;
        Sc[r][c0+0] = make_float2(vr.x, vi.x);
        Sc[r][c0+1] = make_float2(vr.y, vi.y);
        Sc[r][c0+2] = make_float2(vr.z, vi.z);
        Sc[r][c0+3] = make_float2(vr.w, vi.w);
        if (lane < 32) {
            const float4* hr4 = (const float4*)(h_re + bs * 128);
            const float4* hi4 = (const float4*)(h_im + bs * 128);
            float4 hr = hr4[lane], hi = hi4[lane];
            int row = lane >> 1, col = (lane & 1) << 2;
            float2 v0 = make_float2(hr.x, hi.x), v1 = make_float2(hr.y, hi.y);
            float2 v2 = make_float2(hr.z, hi.z), v3 = make_float2(hr.w, hi.w);
            Hc[row][col+0] = v0; Hc[row][col+1] = v1; Hc[row][col+2] = v2; Hc[row][col+3] = v3;
            Sc[row][16+col+0] = v0; Sc[row][16+col+1] = v1; Sc[row][16+col+2] = v2; Sc[row][16+col+3] = v3;
        }
        if (lane < 16) Sc[lane][24] = make_float2(y_re[bs*16+lane], y_im[bs*16+lane]);
        if (lane < 32) ((float*)llrD_)[lane] = prior[bs*32 + lane];
    }
    WSYNC();

    // ---- outer unnormalized GJ on [S | h y]: diagonalize S, RHS -> D*X ----
    {
        const int j0 = lane & 15;
        for (int k = 0; k < 16; ++k) {
            float2 piv = Sc[k][k];                       // 64-way broadcast
            float id = rcpf(piv.x*piv.x + piv.y*piv.y);
            float ipr = piv.x*id, ipi = -piv.y*id;       // 1/piv
            int j1 = k + 1 + j0, j2 = j1 + 16;
            float2 rk0 = make_float2(0.f, 0.f), rk1 = make_float2(0.f, 0.f);
            if (j1 < 25) rk0 = Sc[k][j1];
            if (j2 < 25) rk1 = Sc[k][j2];
            #pragma unroll
            for (int p = 0; p < 4; ++p) {
                int i = (lane >> 4) + (p << 2);
                float2 aik = Sc[i][k];                   // 16-way broadcast
                float mr = aik.x*ipr - aik.y*ipi;
                float mi = aik.x*ipi + aik.y*ipr;
                if (i == k) { mr = 0.f; mi = 0.f; }
                if (j1 < 25) {
                    float2 a = Sc[i][j1];
                    a.x -= mr*rk0.x - mi*rk0.y;
                    a.y -= mr*rk0.y + mi*rk0.x;
                    Sc[i][j1] = a;
                }
                if (j2 < 25) {
                    float2 a = Sc[i][j2];
                    a.x -= mr*rk1.x - mi*rk1.y;
                    a.y -= mr*rk1.y + mi*rk1.x;
                    Sc[i][j2] = a;
                }
            }
            WSYNC();
        }
    }
    // ---- scale RHS by 1/diag: X = S^-1 [h|y] ----
    {
        int i2 = lane >> 2, c = lane & 3;
        float2 d = Sc[i2][i2];
        float id = rcpf(d.x*d.x + d.y*d.y);
        float ipr = d.x*id, ipi = -d.y*id;
        #pragma unroll
        for (int q = 0; q < 3; ++q) {
            int j = 16 + c + (q << 2);
            if (j < 25) {
                float2 v = Sc[i2][j];
                Sc[i2][j] = make_float2(v.x*ipr - v.y*ipi, v.x*ipi + v.y*ipr);
            }
        }
    }
    WSYNC();

    // ---- Gram g[i][j] = (h^H S^-1 h)[i][j] (1/lane), y_mf folded in ----
    const int s = lane >> 3, u = lane & 7;   // (i,j) == (s,u) mapping everywhere below
    float g_re = 0.f, g_im = 0.f, ym_r = 0.f, ym_i = 0.f;
    #pragma unroll
    for (int m = 0; m < 16; ++m) {
        float2 h = Hc[m][s];
        float2 x = Sc[m][16 + u];
        float2 xy = Sc[m][24];
        g_re += h.x*x.x + h.y*x.y;      // conj(h)*x
        g_im += h.x*x.y - h.y*x.x;
        ym_r += h.x*xy.x + h.y*xy.y;
        ym_i += h.x*xy.y - h.y*xy.x;
    }
    if (u == 0) ymc_[s] = make_float2(ym_r, ym_i);
    WSYNC();

    const float pr = pt_re(u), pi2 = pt_im(u), pe = pr*pr + pi2*pi2;  // pt(u+8) = (-pr, pi2)
    float llr_a_reg = 0.f;

    for (int it = 0; it < 2; ++it) {
        // log-sigmoid table: one distinct value per lane
        {
            int ts = lane >> 3, tk = (lane >> 1) & 3, sg = lane & 1;
            float v = llrD_[ts][tk];
            float x = sg ? v : -v;
            lsig[lane] = fminf(x, 0.f) - log1pf(__expf(-fabsf(x)));
        }
        if (lane < 32) llr_a_reg = ((float*)llrD_)[lane];
        WSYNC();
        // symbol logits for p=u (l0) and p=u+8 (l1), in registers
        int base = s << 3;
        float lc = lsig[base | 2 | ((u >> 2) & 1)]
                 + lsig[base | 4 | ((u >> 1) & 1)]
                 + lsig[base | 6 | (u & 1)];
        float l0 = lc + lsig[base];
        float l1 = lc + lsig[base | 1];
        // moments: butterfly over the 8 lanes of stream s
        {
            float mx = fmaxf(l0, l1);
            mx = fmaxf(mx, __shfl_xor(mx, 1));
            mx = fmaxf(mx, __shfl_xor(mx, 2));
            mx = fmaxf(mx, __shfl_xor(mx, 4));
            float w0 = __expf(l0 - mx), w1 = __expf(l1 - mx);
            float a = w0 + w1, dw = w0 - w1;
            float se = a, mr = dw * pr, mi = a * pi2, e2 = a * pe;
            se += __shfl_xor(se,1); mr += __shfl_xor(mr,1); mi += __shfl_xor(mi,1); e2 += __shfl_xor(e2,1);
            se += __shfl_xor(se,2); mr += __shfl_xor(mr,2); mi += __shfl_xor(mi,2); e2 += __shfl_xor(e2,2);
            se += __shfl_xor(se,4); mr += __shfl_xor(mr,4); mi += __shfl_xor(mi,4); e2 += __shfl_xor(e2,4);
            if (u == 0) {
                float inv = rcpf(se);
                float mxr = mr*inv, mxi = mi*inv;
                xc_[s] = make_float2(mxr, mxi);
                vx_[s] = e2*inv - (mxr*mxr + mxi*mxi);
            }
        }
        WSYNC();
        // setup: b_i = y_mf[i] - (g x)_i (replicated), A = I + g diag(var), C = g
        float2 xj = xc_[u];
        float vj = vx_[u];
        float tr = g_re*xj.x - g_im*xj.y;
        float ti = g_re*xj.y + g_im*xj.x;
        tr += __shfl_xor(tr,1); ti += __shfl_xor(ti,1);
        tr += __shfl_xor(tr,2); ti += __shfl_xor(ti,2);
        tr += __shfl_xor(tr,4); ti += __shfl_xor(ti,4);
        float2 ym = ymc_[s];
        float br_ = ym.x - tr, bi_ = ym.y - ti;
        float Ar = g_re*vj + ((s == u) ? 1.f : 0.f);
        float Ai = g_im*vj;
        float Cr = g_re, Ci = g_im;
        // inner unnormalized GJ on [A | b | C], all registers + shuffles
        #pragma unroll
        for (int k = 0; k < 8; ++k) {
            int rowsrc = (k << 3) | u;      // lane holding (k, u)
            int colsrc = (s << 3) | k;      // lane holding (s, k)
            float pvr = __shfl(Ar, k * 9);  // A[k][k]
            float pvi = __shfl(Ai, k * 9);
            float rAr = __shfl(Ar, rowsrc), rAi = __shfl(Ai, rowsrc);
            float rCr = __shfl(Cr, rowsrc), rCi = __shfl(Ci, rowsrc);
            float rbr = __shfl(br_, rowsrc), rbi = __shfl(bi_, rowsrc);
            float cAr = __shfl(Ar, colsrc), cAi = __shfl(Ai, colsrc);
            float id2 = rcpf(pvr*pvr + pvi*pvi);
            float ipr2 = pvr*id2, ipi2 = -pvi*id2;
            float mr2 = cAr*ipr2 - cAi*ipi2;
            float mi2 = cAr*ipi2 + cAi*ipr2;
            if (s == k) { mr2 = 0.f; mi2 = 0.f; }
            Ar  -= mr2*rAr - mi2*rAi;  Ai  -= mr2*rAi + mi2*rAr;
            Cr  -= mr2*rCr - mi2*rCi;  Ci  -= mr2*rCi + mi2*rCr;
            br_ -= mr2*rbr - mi2*rbi;  bi_ -= mr2*rbi + mi2*rbr;
        }
        // extraction on diagonal lanes: z = (w + Cii*x)/mu, no_eff
        if (s == u) {
            float id3 = rcpf(Ar*Ar + Ai*Ai);
            float ipr3 = Ar*id3, ipi3 = -Ai*id3;
            float wr = br_*ipr3 - bi_*ipi3;
            float wi = br_*ipi3 + bi_*ipr3;
            float ccr = Cr*ipr3 - Ci*ipi3;
            float cci = Cr*ipi3 + Ci*ipr3;
            float mu = ccr;
            float im = rcpf(mu);
            float zr = (wr + ccr*xj.x - cci*xj.y) * im;
            float zi = (wi + ccr*xj.y + cci*xj.x) * im;
            xc_[s] = make_float2(zr, zi);
            ne_[s] = fmaxf(1.f - vx_[s]*mu, EPS_F) * im;
        }
        WSYNC();
        // demap: 2 points per lane
        {
            float2 xh = xc_[s];
            float idn = rcpf(ne_[s]);
            float dr0 = xh.x - pr, dr1 = xh.x + pr, di = xh.y - pi2;
            logit_[s][u]     = l0 - (dr0*dr0 + di*di) * idn;
            logit_[s][u + 8] = l1 - (dr1*dr1 + di*di) * idn;
        }
        WSYNC();
        // max-log LLR: lane = (s2, bit kb, half); max over 8 matching points
        {
            int s2 = lane >> 3, kb = (lane >> 1) & 3, half = lane & 1;
            int bitpos = 3 - kb;
            float m = -1e30f;
            #pragma unroll
            for (int q = 0; q < 8; ++q) {
                int low  = q & ((1 << bitpos) - 1);
                int high = (q >> bitpos) << (bitpos + 1);
                int p = high | (half << bitpos) | low;
                m = fmaxf(m, logit_[s2][p]);
            }
            float other = __shfl_xor(m, 1);
            if (half == 1) llrD_[s2][kb] = m - other;   // l1 - l0
        }
        WSYNC();
    }

    if (lane < 32) out[bs*32 + lane] = ((float*)llrD_)[lane] - llr_a_reg;
}

extern "C" void kernel_launch(void* const* d_in, const int* in_sizes, int n_in,
                              void* d_out, int out_size, void* d_ws, size_t ws_size,
                              hipStream_t stream) {
    const float* y_re  = (const float*)d_in[0];
    const float* y_im  = (const float*)d_in[1];
    const float* h_re  = (const float*)d_in[2];
    const float* h_im  = (const float*)d_in[3];
    const float* prior = (const float*)d_in[4];
    const float* s_re  = (const float*)d_in[5];
    const float* s_im  = (const float*)d_in[6];
    float* out = (float*)d_out;

    const int B = in_sizes[0] / 16;
    mmse_pic_kernel<<<dim3(B), dim3(64), 0, stream>>>(
        y_re, y_im, h_re, h_im, prior, s_re, s_im, out);
}